// Round 2
// baseline (1660.273 us; speedup 1.0000x reference)
//
#include <hip/hip_runtime.h>
#include <hip/hip_fp16.h>

#define BB 512
#define TT 512
#define EE 100
#define HH 40
#define GG 120   // 3*HH
#define TC 64    // timesteps per chunk
#define NC 8     // chunks (TT/TC)

__device__ __forceinline__ float sigmoid_(float x) {
    return 1.0f / (1.0f + __expf(-x));
}
// tanh via exp, safe at both tails
__device__ __forceinline__ float tanhfast_(float x) {
    float e = __expf(2.0f * x);
    return 1.0f - 2.0f / (e + 1.0f);
}

// Chunked input-side GEMM. One launch computes gx for BOTH directions of the
// chunk pair (fwd chunk ci, bwd chunk NC-1-ci) into gx[2][B][TC][GG].
// blockIdx.x = batch b (a 64-row tile == exactly the 64 tloc of one batch),
// blockIdx.y = 64-col tile (2 tiles cover GG=120), blockIdx.z = dir.
// GATHER=true: X row = emb[text[b,t]], K=100. Else X = out0 fp16, stride K=80.
template<int K, bool GATHER>
__global__ __launch_bounds__(256) void gx_chunk(
    const int ci,
    const int* __restrict__ text, const float* __restrict__ emb,
    const __half* __restrict__ Xh,
    const float* __restrict__ Wf, const float* __restrict__ bf,
    const float* __restrict__ Wb, const float* __restrict__ bb,
    float* __restrict__ gx)
{
    constexpr int KP = K + 1;          // odd stride -> conflict-free LDS banks
    __shared__ float Xs[64][KP];
    __shared__ float Ws[64][KP];
    const int tid = threadIdx.x;
    const int b   = blockIdx.x;
    const int c0  = blockIdx.y * 64;
    const int dir = blockIdx.z;
    const int chunk = dir ? (NC - 1 - ci) : ci;
    const int tbase = chunk * TC;
    const float* W    = dir ? Wb : Wf;
    const float* bias = dir ? bb : bf;

    for (int idx = tid; idx < 64 * K; idx += 256) {
        int rr = idx / K, k = idx - rr * K;   // rr = tloc
        int t = tbase + rr;
        float v;
        if (GATHER) {
            int tok = text[b * TT + t];
            v = emb[(size_t)tok * K + k];
        } else {
            v = __half2float(Xh[((size_t)b * TT + t) * K + k]);
        }
        Xs[rr][k] = v;
    }
    for (int idx = tid; idx < 64 * K; idx += 256) {
        int c = idx / K, k = idx - c * K;
        Ws[c][k] = (c0 + c < GG) ? W[(size_t)(c0 + c) * K + k] : 0.0f;
    }
    __syncthreads();

    const int tx = tid & 15, ty = tid >> 4;
    float acc[4][4] = {};
    for (int k = 0; k < K; ++k) {
        float a0 = Xs[ty*4+0][k], a1 = Xs[ty*4+1][k], a2 = Xs[ty*4+2][k], a3 = Xs[ty*4+3][k];
        float w0 = Ws[tx*4+0][k], w1 = Ws[tx*4+1][k], w2 = Ws[tx*4+2][k], w3 = Ws[tx*4+3][k];
        acc[0][0] = fmaf(a0,w0,acc[0][0]); acc[0][1] = fmaf(a0,w1,acc[0][1]);
        acc[0][2] = fmaf(a0,w2,acc[0][2]); acc[0][3] = fmaf(a0,w3,acc[0][3]);
        acc[1][0] = fmaf(a1,w0,acc[1][0]); acc[1][1] = fmaf(a1,w1,acc[1][1]);
        acc[1][2] = fmaf(a1,w2,acc[1][2]); acc[1][3] = fmaf(a1,w3,acc[1][3]);
        acc[2][0] = fmaf(a2,w0,acc[2][0]); acc[2][1] = fmaf(a2,w1,acc[2][1]);
        acc[2][2] = fmaf(a2,w2,acc[2][2]); acc[2][3] = fmaf(a2,w3,acc[2][3]);
        acc[3][0] = fmaf(a3,w0,acc[3][0]); acc[3][1] = fmaf(a3,w1,acc[3][1]);
        acc[3][2] = fmaf(a3,w2,acc[3][2]); acc[3][3] = fmaf(a3,w3,acc[3][3]);
    }
    const size_t rowB = ((size_t)dir * BB + b) * TC;
    #pragma unroll
    for (int i = 0; i < 4; ++i) {
        size_t r = rowB + ty*4 + i;
        #pragma unroll
        for (int j2 = 0; j2 < 4; ++j2) {
            int c = c0 + tx*4 + j2;
            if (c < GG) gx[r * GG + c] = acc[i][j2] + bias[c];
        }
    }
}

// One wave per (batch, dir), TC sequential steps per launch; h carried in
// hcar between launches. Lane j owns channel j; Whh rows {j,40+j,80+j} in
// VGPRs. h broadcast via 40-float LDS vector (wave-local, in-order DS, no
// barrier). layer0: writes out0 fp16. layer1: accumulates pooling into
// sumb/maxb across chunk launches (init at ci==0 — ws is re-poisoned).
__global__ __launch_bounds__(64) void gru_scan_chunk(
    const int ci, const int layer,
    const float* __restrict__ gx,
    const float* __restrict__ WhhF, const float* __restrict__ bhhF,
    const float* __restrict__ WhhB, const float* __restrict__ bhhB,
    const int* __restrict__ lens,
    __half* __restrict__ out0,
    float* __restrict__ hcar,
    float* __restrict__ hlast,
    float* __restrict__ sumb, float* __restrict__ maxb)
{
    __shared__ __align__(16) float hsh[HH];
    const int b   = blockIdx.x;
    const int dir = blockIdx.y;
    const int j   = threadIdx.x;
    if (j >= HH) return;

    const float* Whh = dir ? WhhB : WhhF;
    const float* bhh = dir ? bhhB : bhhF;

    float Wr[HH], Wz[HH], Wn[HH];
    #pragma unroll
    for (int k = 0; k < HH; ++k) {
        Wr[k] = Whh[(size_t)(0*HH + j) * HH + k];
        Wz[k] = Whh[(size_t)(1*HH + j) * HH + k];
        Wn[k] = Whh[(size_t)(2*HH + j) * HH + k];
    }
    const float br = bhh[j], bz = bhh[HH + j], bn = bhh[2*HH + j];
    const int len = lens[b];
    const int chunk = dir ? (NC - 1 - ci) : ci;
    const int tbase = chunk * TC;

    float h = (ci == 0) ? 0.0f : hcar[(size_t)(dir * BB + b) * HH + j];
    hsh[j] = h;
    float psum = 0.0f, pmax = -3.4e38f;
    const size_t gxRow = ((size_t)dir * BB + b) * TC;

    const float4* h4 = (const float4*)hsh;
    for (int s = 0; s < TC; ++s) {
        const int tloc = dir ? (TC - 1 - s) : s;
        const int t = tbase + tloc;
        const float* gp = gx + (gxRow + tloc) * GG;
        const float gr = gp[j], gz = gp[HH + j], gn = gp[2*HH + j];

        float ghr = br, ghz = bz, ghn = bn;
        #pragma unroll
        for (int q = 0; q < HH/4; ++q) {
            float4 hv = h4[q];
            ghr = fmaf(Wr[4*q+0], hv.x, ghr);
            ghz = fmaf(Wz[4*q+0], hv.x, ghz);
            ghn = fmaf(Wn[4*q+0], hv.x, ghn);
            ghr = fmaf(Wr[4*q+1], hv.y, ghr);
            ghz = fmaf(Wz[4*q+1], hv.y, ghz);
            ghn = fmaf(Wn[4*q+1], hv.y, ghn);
            ghr = fmaf(Wr[4*q+2], hv.z, ghr);
            ghz = fmaf(Wz[4*q+2], hv.z, ghz);
            ghn = fmaf(Wn[4*q+2], hv.z, ghn);
            ghr = fmaf(Wr[4*q+3], hv.w, ghr);
            ghz = fmaf(Wz[4*q+3], hv.w, ghz);
            ghn = fmaf(Wn[4*q+3], hv.w, ghn);
        }
        const float rr = sigmoid_(gr + ghr);
        const float zz = sigmoid_(gz + ghz);
        const float nn = tanhfast_(gn + rr * ghn);
        const float hn = (1.0f - zz) * nn + zz * h;
        const bool v = (t < len);
        h = v ? hn : h;               // freeze past length
        const float ov = v ? hn : 0.0f;
        if (layer == 0) {
            out0[((size_t)b * TT + t) * (2*HH) + dir*HH + j] = __float2half(ov);
        } else {
            psum += ov;
            if (v) pmax = fmaxf(pmax, hn);
        }
        hsh[j] = h;                   // broadcast for next step (in-order DS)
    }
    hcar[(size_t)(dir * BB + b) * HH + j] = h;
    if (ci == NC - 1)
        hlast[((size_t)(layer * 2 + dir) * BB + b) * HH + j] = h;
    if (layer == 1) {
        const size_t pi = (size_t)b * (2*HH) + dir*HH + j;
        if (ci == 0) { sumb[pi] = psum;          maxb[pi] = pmax; }
        else         { sumb[pi] += psum;         maxb[pi] = fmaxf(maxb[pi], pmax); }
    }
}

// pool_cat = [hb1, hf1, hb0, hf0, avg(80), max(80)] -> fc1(128) -> lrelu -> fc2(1)
__global__ __launch_bounds__(128) void fc_kernel(
    const float* __restrict__ hlast, const float* __restrict__ sumb,
    const float* __restrict__ maxb, const int* __restrict__ lens,
    const float* __restrict__ fc1W, const float* __restrict__ fc1b,
    const float* __restrict__ fc2W, const float* __restrict__ fc2b,
    float* __restrict__ out)
{
    __shared__ float pool[8 * HH];
    __shared__ float red[128];
    const int b = blockIdx.x, tid = threadIdx.x;
    // hlast slots: 0=l0f(hf0), 1=l0b(hb0), 2=l1f(hf1), 3=l1b(hb1)
    if (tid < HH) {
        pool[tid]        = hlast[(size_t)(3*BB + b) * HH + tid]; // hb1
        pool[HH + tid]   = hlast[(size_t)(2*BB + b) * HH + tid]; // hf1
        pool[2*HH + tid] = hlast[(size_t)(1*BB + b) * HH + tid]; // hb0
        pool[3*HH + tid] = hlast[(size_t)(0*BB + b) * HH + tid]; // hf0
    }
    const float invLen = 1.0f / (float)lens[b];
    if (tid < 2*HH) {
        pool[4*HH + tid] = sumb[(size_t)b * 2*HH + tid] * invLen;
        pool[6*HH + tid] = maxb[(size_t)b * 2*HH + tid];
    }
    __syncthreads();
    float acc = fc1b[tid];
    for (int k = 0; k < 8*HH; ++k)
        acc = fmaf(pool[k], fc1W[(size_t)tid * (8*HH) + k], acc);
    float v = (acc >= 0.0f) ? acc : 0.01f * acc;
    red[tid] = v * fc2W[tid];
    __syncthreads();
    for (int s = 64; s > 0; s >>= 1) {
        if (tid < s) red[tid] += red[tid + s];
        __syncthreads();
    }
    if (tid == 0) out[b] = red[0] + fc2b[0];
}

extern "C" void kernel_launch(void* const* d_in, const int* in_sizes, int n_in,
                              void* d_out, int out_size, void* d_ws, size_t ws_size,
                              hipStream_t stream) {
    const int*   text  = (const int*)d_in[0];
    const int*   lens  = (const int*)d_in[1];
    const float* emb   = (const float*)d_in[2];
    const float* Wih0f = (const float*)d_in[3];
    const float* Whh0f = (const float*)d_in[4];
    const float* bih0f = (const float*)d_in[5];
    const float* bhh0f = (const float*)d_in[6];
    const float* Wih0b = (const float*)d_in[7];
    const float* Whh0b = (const float*)d_in[8];
    const float* bih0b = (const float*)d_in[9];
    const float* bhh0b = (const float*)d_in[10];
    const float* Wih1f = (const float*)d_in[11];
    const float* Whh1f = (const float*)d_in[12];
    const float* bih1f = (const float*)d_in[13];
    const float* bhh1f = (const float*)d_in[14];
    const float* Wih1b = (const float*)d_in[15];
    const float* Whh1b = (const float*)d_in[16];
    const float* bih1b = (const float*)d_in[17];
    const float* bhh1b = (const float*)d_in[18];
    const float* fc1W  = (const float*)d_in[19];
    const float* fc1b  = (const float*)d_in[20];
    const float* fc2W  = (const float*)d_in[21];
    const float* fc2b  = (const float*)d_in[22];
    float* out = (float*)d_out;

    // workspace (bytes): gx fp32 [2,B,TC,GG] = 31.46MB | out0 fp16 [B,T,80] =
    // 41.94MB | hcar [2,B,H] | hlast [4,B,H] | sumb,maxb [B,2H] ~= 74.2MB total
    char* ws = (char*)d_ws;
    float*  gx    = (float*)ws;                 ws += (size_t)2*BB*TC*GG*4;
    __half* out0  = (__half*)ws;                ws += (size_t)BB*TT*2*HH*2;
    float*  hcar  = (float*)ws;                 ws += (size_t)2*BB*HH*4;
    float*  hlast = (float*)ws;                 ws += (size_t)4*BB*HH*4;
    float*  sumb  = (float*)ws;                 ws += (size_t)BB*2*HH*4;
    float*  maxb  = (float*)ws;

    const dim3 ggrid(BB, 2, 2);   // (batch-tile, col-tile, dir)
    const dim3 sgrid(BB, 2);      // (batch, dir)

    // layer 0: 8 chunk pairs of (gemm, scan)
    for (int ci = 0; ci < NC; ++ci) {
        gx_chunk<EE, true><<<ggrid, 256, 0, stream>>>(ci, text, emb, nullptr,
            Wih0f, bih0f, Wih0b, bih0b, gx);
        gru_scan_chunk<<<sgrid, 64, 0, stream>>>(ci, 0, gx,
            Whh0f, bhh0f, Whh0b, bhh0b, lens, out0, hcar, hlast, nullptr, nullptr);
    }
    // layer 1: same, reading out0 fp16, fused pooling
    for (int ci = 0; ci < NC; ++ci) {
        gx_chunk<2*HH, false><<<ggrid, 256, 0, stream>>>(ci, nullptr, nullptr, out0,
            Wih1f, bih1f, Wih1b, bih1b, gx);
        gru_scan_chunk<<<sgrid, 64, 0, stream>>>(ci, 1, gx,
            Whh1f, bhh1f, Whh1b, bhh1b, lens, nullptr, hcar, hlast, sumb, maxb);
    }
    // head
    fc_kernel<<<BB, 128, 0, stream>>>(hlast, sumb, maxb, lens,
        fc1W, fc1b, fc2W, fc2b, out);
}

// Round 3
// 970.013 us; speedup vs baseline: 1.7116x; 1.7116x over previous
//
#include <hip/hip_runtime.h>
#include <hip/hip_fp16.h>

#define BB 512
#define TT 512
#define EE 100
#define HH 40
#define GG 120   // 3*HH
#define TC 64    // timesteps per chunk
#define NC 8     // chunks

__device__ __forceinline__ float sigmoid_(float x) {
    return 1.0f / (1.0f + __expf(-x));
}
__device__ __forceinline__ float tanhfast_(float x) {
    float e = __expf(2.0f * x);
    return 1.0f - 2.0f / (e + 1.0f);
}

// Fused launch: blocks [0,nScan) run the recurrent scan for chunk cs (reading
// gxR); blocks [nScan, gridDim) run the input-side GEMM for chunk cg (writing
// gxW). The two halves share no data -> no ordering assumption (G16-safe).
// Scan blocks first so the latency-bound chains start immediately; GEMM
// blocks fill the remaining CUs -> per-launch time ~ max(gemm, scan).
//
// GEMM: k-major LDS tiles. Xs[k][r], Ws[k][c]: compute reads are float4
// (X: 16-lane broadcast, W: 2-way = free). Load phase maps r=idx&63 so LDS
// writes hit bank lane%32 (2-way, free). gx written fp16.
//
// Scan: one wave per (b,dir) chain, lane j owns channel j, Whh in VGPRs,
// h broadcast via per-wave LDS vector (in-order DS, no barrier), next-step
// gx prefetched as raw halfs (cvt deferred one iteration).
template<int K, bool GATHER>
__global__ __launch_bounds__(256) void fused_kernel(
    const int cg, const int cs, const int nScan,
    const int* __restrict__ text, const float* __restrict__ emb,
    const __half* __restrict__ Xh,
    const float* __restrict__ Wf, const float* __restrict__ bf,
    const float* __restrict__ Wb, const float* __restrict__ bb,
    __half* __restrict__ gxW, const __half* __restrict__ gxR,
    const float* __restrict__ WhhF, const float* __restrict__ bhhF,
    const float* __restrict__ WhhB, const float* __restrict__ bhhB,
    const int* __restrict__ lens,
    __half* __restrict__ out0,
    float* __restrict__ hcar, float* __restrict__ hlast,
    float* __restrict__ sumb, float* __restrict__ maxb)
{
    __shared__ float Xs[K * 64];
    __shared__ float Ws[K * 64];
    __shared__ __align__(16) float hsh[4][48];
    const int tid = threadIdx.x;

    if ((int)blockIdx.x < nScan) {
        // ================= scan =================
        const int wave = tid >> 6, j = tid & 63;
        if (j >= HH) return;
        const int chain = blockIdx.x * 4 + wave;
        const int dir = chain >> 9;
        const int b   = chain & (BB - 1);
        const float* Whh = dir ? WhhB : WhhF;
        const float* bhh = dir ? bhhB : bhhF;

        float Wr[HH], Wz[HH], Wn[HH];
        const float4* wr4 = (const float4*)(Whh + (size_t)(0*HH + j) * HH);
        const float4* wz4 = (const float4*)(Whh + (size_t)(1*HH + j) * HH);
        const float4* wn4 = (const float4*)(Whh + (size_t)(2*HH + j) * HH);
        #pragma unroll
        for (int q = 0; q < HH/4; ++q) {
            float4 a = wr4[q]; Wr[4*q]=a.x; Wr[4*q+1]=a.y; Wr[4*q+2]=a.z; Wr[4*q+3]=a.w;
            float4 c = wz4[q]; Wz[4*q]=c.x; Wz[4*q+1]=c.y; Wz[4*q+2]=c.z; Wz[4*q+3]=c.w;
            float4 d = wn4[q]; Wn[4*q]=d.x; Wn[4*q+1]=d.y; Wn[4*q+2]=d.z; Wn[4*q+3]=d.w;
        }
        const float br = bhh[j], bz = bhh[HH + j], bn = bhh[2*HH + j];
        const int len = lens[b];
        const int chunk = dir ? (NC - 1 - cs) : cs;
        const int tbase = chunk * TC;

        float h = (cs == 0) ? 0.0f : hcar[(size_t)(dir * BB + b) * HH + j];
        hsh[wave][j] = h;
        float psum = 0.0f, pmax = -3.4e38f;
        const size_t gxRow = ((size_t)dir * BB + b) * TC;

        const __half* gp0 = gxR + (gxRow + (dir ? (TC - 1) : 0)) * GG;
        __half hr = gp0[j], hz = gp0[HH + j], hn_ = gp0[2*HH + j];

        const float4* h4 = (const float4*)hsh[wave];
        for (int s = 0; s < TC; ++s) {
            const int tloc = dir ? (TC - 1 - s) : s;
            const int t = tbase + tloc;
            __half nhr = __float2half(0.f), nhz = nhr, nhn = nhr;
            if (s + 1 < TC) {   // prefetch next step's gx (use next iter)
                const __half* gq = gxR + (gxRow + (dir ? (TC - 2 - s) : (s + 1))) * GG;
                nhr = gq[j]; nhz = gq[HH + j]; nhn = gq[2*HH + j];
            }
            const float gr = __half2float(hr), gz = __half2float(hz), gn = __half2float(hn_);
            float ghr = br, ghz = bz, ghn = bn;
            #pragma unroll
            for (int q = 0; q < HH/4; ++q) {
                float4 hv = h4[q];
                ghr = fmaf(Wr[4*q+0], hv.x, ghr);
                ghz = fmaf(Wz[4*q+0], hv.x, ghz);
                ghn = fmaf(Wn[4*q+0], hv.x, ghn);
                ghr = fmaf(Wr[4*q+1], hv.y, ghr);
                ghz = fmaf(Wz[4*q+1], hv.y, ghz);
                ghn = fmaf(Wn[4*q+1], hv.y, ghn);
                ghr = fmaf(Wr[4*q+2], hv.z, ghr);
                ghz = fmaf(Wz[4*q+2], hv.z, ghz);
                ghn = fmaf(Wn[4*q+2], hv.z, ghn);
                ghr = fmaf(Wr[4*q+3], hv.w, ghr);
                ghz = fmaf(Wz[4*q+3], hv.w, ghz);
                ghn = fmaf(Wn[4*q+3], hv.w, ghn);
            }
            const float rr = sigmoid_(gr + ghr);
            const float zz = sigmoid_(gz + ghz);
            const float nn = tanhfast_(gn + rr * ghn);
            const float hn = (1.0f - zz) * nn + zz * h;
            const bool v = (t < len);
            h = v ? hn : h;
            const float ov = v ? hn : 0.0f;
            if (GATHER) {  // layer 0: materialize out0 (fp16)
                out0[((size_t)b * TT + t) * (2*HH) + dir*HH + j] = __float2half(ov);
            } else {       // layer 1: fused pooling
                psum += ov;
                if (v) pmax = fmaxf(pmax, hn);
            }
            hsh[wave][j] = h;
            hr = nhr; hz = nhz; hn_ = nhn;
        }
        hcar[(size_t)(dir * BB + b) * HH + j] = h;
        const int layer = GATHER ? 0 : 1;
        if (cs == NC - 1)
            hlast[((size_t)(layer * 2 + dir) * BB + b) * HH + j] = h;
        if (!GATHER) {
            const size_t pi = (size_t)b * (2*HH) + dir*HH + j;
            if (cs == 0) { sumb[pi] = psum;        maxb[pi] = pmax; }
            else         { sumb[pi] += psum;       maxb[pi] = fmaxf(maxb[pi], pmax); }
        }
        return;
    }

    // ================= gemm =================
    const int gid = blockIdx.x - nScan;
    const int b   = gid & (BB - 1);
    const int ct  = (gid >> 9) & 1;
    const int dir = gid >> 10;
    const int chunk = dir ? (NC - 1 - cg) : cg;
    const int tbase = chunk * TC;
    const float* W    = dir ? Wb : Wf;
    const float* bias = dir ? bb : bf;
    const int c0 = ct * 64;
    constexpr int KQ = K / 4;

    // stage X (k-major): Xs[k][r]
    if (GATHER) {
        for (int idx = tid; idx < 64 * KQ; idx += 256) {
            const int r = idx & 63, q = idx >> 6;
            const int tok = text[b * TT + tbase + r];
            const float4 v = ((const float4*)emb)[(size_t)tok * KQ + q];
            Xs[(4*q+0)*64 + r] = v.x;
            Xs[(4*q+1)*64 + r] = v.y;
            Xs[(4*q+2)*64 + r] = v.z;
            Xs[(4*q+3)*64 + r] = v.w;
        }
    } else {
        constexpr int KQ8 = K / 8;
        for (int idx = tid; idx < 64 * KQ8; idx += 256) {
            const int r = idx & 63, q = idx >> 6;
            const float4 v = ((const float4*)Xh)[((size_t)b * TT + tbase + r) * KQ8 + q];
            const __half2* hp = (const __half2*)&v;
            #pragma unroll
            for (int i2 = 0; i2 < 4; ++i2) {
                const float2 f2 = __half22float2(hp[i2]);
                Xs[(8*q + 2*i2 + 0)*64 + r] = f2.x;
                Xs[(8*q + 2*i2 + 1)*64 + r] = f2.y;
            }
        }
    }
    // stage W (k-major): Ws[k][c]
    for (int idx = tid; idx < 64 * KQ; idx += 256) {
        const int c = idx & 63, q = idx >> 6;
        float4 v = make_float4(0.f, 0.f, 0.f, 0.f);
        if (c0 + c < GG) v = ((const float4*)W)[(size_t)(c0 + c) * KQ + q];
        Ws[(4*q+0)*64 + c] = v.x;
        Ws[(4*q+1)*64 + c] = v.y;
        Ws[(4*q+2)*64 + c] = v.z;
        Ws[(4*q+3)*64 + c] = v.w;
    }
    __syncthreads();

    const int tx = tid & 15, ty = tid >> 4;
    float acc[4][4] = {};
    #pragma unroll 4
    for (int k = 0; k < K; ++k) {
        const float4 xa = *(const float4*)(Xs + k*64 + (ty << 2));
        const float4 wv = *(const float4*)(Ws + k*64 + (tx << 2));
        acc[0][0] = fmaf(xa.x, wv.x, acc[0][0]); acc[0][1] = fmaf(xa.x, wv.y, acc[0][1]);
        acc[0][2] = fmaf(xa.x, wv.z, acc[0][2]); acc[0][3] = fmaf(xa.x, wv.w, acc[0][3]);
        acc[1][0] = fmaf(xa.y, wv.x, acc[1][0]); acc[1][1] = fmaf(xa.y, wv.y, acc[1][1]);
        acc[1][2] = fmaf(xa.y, wv.z, acc[1][2]); acc[1][3] = fmaf(xa.y, wv.w, acc[1][3]);
        acc[2][0] = fmaf(xa.z, wv.x, acc[2][0]); acc[2][1] = fmaf(xa.z, wv.y, acc[2][1]);
        acc[2][2] = fmaf(xa.z, wv.z, acc[2][2]); acc[2][3] = fmaf(xa.z, wv.w, acc[2][3]);
        acc[3][0] = fmaf(xa.w, wv.x, acc[3][0]); acc[3][1] = fmaf(xa.w, wv.y, acc[3][1]);
        acc[3][2] = fmaf(xa.w, wv.z, acc[3][2]); acc[3][3] = fmaf(xa.w, wv.w, acc[3][3]);
    }

    const int c = c0 + (tx << 2);
    if (c < GG) {
        const float b0v = bias[c], b1v = bias[c+1], b2v = bias[c+2], b3v = bias[c+3];
        const size_t rowB = ((size_t)dir * BB + b) * TC;
        #pragma unroll
        for (int i = 0; i < 4; ++i) {
            const int tloc = (ty << 2) + i;
            union { float2 f; __half2 h[2]; } u;
            u.h[0] = __floats2half2_rn(acc[i][0] + b0v, acc[i][1] + b1v);
            u.h[1] = __floats2half2_rn(acc[i][2] + b2v, acc[i][3] + b3v);
            *(float2*)(gxW + (rowB + tloc) * GG + c) = u.f;
        }
    }
}

// pool_cat = [hb1, hf1, hb0, hf0, avg(80), max(80)] -> fc1(128) -> lrelu -> fc2(1)
__global__ __launch_bounds__(128) void fc_kernel(
    const float* __restrict__ hlast, const float* __restrict__ sumb,
    const float* __restrict__ maxb, const int* __restrict__ lens,
    const float* __restrict__ fc1W, const float* __restrict__ fc1b,
    const float* __restrict__ fc2W, const float* __restrict__ fc2b,
    float* __restrict__ out)
{
    __shared__ float pool[8 * HH];
    __shared__ float red[128];
    const int b = blockIdx.x, tid = threadIdx.x;
    if (tid < HH) {
        pool[tid]        = hlast[(size_t)(3*BB + b) * HH + tid]; // hb1
        pool[HH + tid]   = hlast[(size_t)(2*BB + b) * HH + tid]; // hf1
        pool[2*HH + tid] = hlast[(size_t)(1*BB + b) * HH + tid]; // hb0
        pool[3*HH + tid] = hlast[(size_t)(0*BB + b) * HH + tid]; // hf0
    }
    const float invLen = 1.0f / (float)lens[b];
    if (tid < 2*HH) {
        pool[4*HH + tid] = sumb[(size_t)b * 2*HH + tid] * invLen;
        pool[6*HH + tid] = maxb[(size_t)b * 2*HH + tid];
    }
    __syncthreads();
    float acc = fc1b[tid];
    for (int k = 0; k < 8*HH; ++k)
        acc = fmaf(pool[k], fc1W[(size_t)tid * (8*HH) + k], acc);
    float v = (acc >= 0.0f) ? acc : 0.01f * acc;
    red[tid] = v * fc2W[tid];
    __syncthreads();
    for (int s = 64; s > 0; s >>= 1) {
        if (tid < s) red[tid] += red[tid + s];
        __syncthreads();
    }
    if (tid == 0) out[b] = red[0] + fc2b[0];
}

extern "C" void kernel_launch(void* const* d_in, const int* in_sizes, int n_in,
                              void* d_out, int out_size, void* d_ws, size_t ws_size,
                              hipStream_t stream) {
    const int*   text  = (const int*)d_in[0];
    const int*   lens  = (const int*)d_in[1];
    const float* emb   = (const float*)d_in[2];
    const float* Wih0f = (const float*)d_in[3];
    const float* Whh0f = (const float*)d_in[4];
    const float* bih0f = (const float*)d_in[5];
    const float* bhh0f = (const float*)d_in[6];
    const float* Wih0b = (const float*)d_in[7];
    const float* Whh0b = (const float*)d_in[8];
    const float* bih0b = (const float*)d_in[9];
    const float* bhh0b = (const float*)d_in[10];
    const float* Wih1f = (const float*)d_in[11];
    const float* Whh1f = (const float*)d_in[12];
    const float* bih1f = (const float*)d_in[13];
    const float* bhh1f = (const float*)d_in[14];
    const float* Wih1b = (const float*)d_in[15];
    const float* Whh1b = (const float*)d_in[16];
    const float* bih1b = (const float*)d_in[17];
    const float* bhh1b = (const float*)d_in[18];
    const float* fc1W  = (const float*)d_in[19];
    const float* fc1b  = (const float*)d_in[20];
    const float* fc2W  = (const float*)d_in[21];
    const float* fc2b  = (const float*)d_in[22];
    float* out = (float*)d_out;

    // ws: gx double-buffer fp16 (2 x 15.73MB) | out0 fp16 (41.94MB) | small
    char* p = (char*)d_ws;
    const size_t gxB = (size_t)2 * BB * TC * GG * sizeof(__half);
    __half* gxb0  = (__half*)p;  p += gxB;
    __half* gxb1  = (__half*)p;  p += gxB;
    __half* out0  = (__half*)p;  p += (size_t)BB * TT * 2 * HH * sizeof(__half);
    float*  hcar  = (float*)p;   p += (size_t)2 * BB * HH * sizeof(float);
    float*  hlast = (float*)p;   p += (size_t)4 * BB * HH * sizeof(float);
    float*  sumb  = (float*)p;   p += (size_t)BB * 2 * HH * sizeof(float);
    float*  maxb  = (float*)p;
    __half* gxb[2] = { gxb0, gxb1 };

    const int NG = BB * 2 * 2;   // 2048 gemm blocks
    const int NS = 256;          // 1024 chains / 4 waves

    // ---- layer 0 ----
    fused_kernel<EE, true><<<NG, 256, 0, stream>>>(0, 0, 0,
        text, emb, nullptr, Wih0f, bih0f, Wih0b, bih0b,
        gxb[0], gxb[0], Whh0f, bhh0f, Whh0b, bhh0b,
        lens, out0, hcar, hlast, sumb, maxb);
    for (int ci = 1; ci < NC; ++ci)
        fused_kernel<EE, true><<<NS + NG, 256, 0, stream>>>(ci, ci - 1, NS,
            text, emb, nullptr, Wih0f, bih0f, Wih0b, bih0b,
            gxb[ci & 1], gxb[(ci - 1) & 1], Whh0f, bhh0f, Whh0b, bhh0b,
            lens, out0, hcar, hlast, sumb, maxb);
    fused_kernel<EE, true><<<NS, 256, 0, stream>>>(0, NC - 1, NS,
        text, emb, nullptr, Wih0f, bih0f, Wih0b, bih0b,
        gxb[0], gxb[(NC - 1) & 1], Whh0f, bhh0f, Whh0b, bhh0b,
        lens, out0, hcar, hlast, sumb, maxb);

    // ---- layer 1 ----
    fused_kernel<2*HH, false><<<NG, 256, 0, stream>>>(0, 0, 0,
        text, emb, out0, Wih1f, bih1f, Wih1b, bih1b,
        gxb[0], gxb[0], Whh1f, bhh1f, Whh1b, bhh1b,
        lens, out0, hcar, hlast, sumb, maxb);
    for (int ci = 1; ci < NC; ++ci)
        fused_kernel<2*HH, false><<<NS + NG, 256, 0, stream>>>(ci, ci - 1, NS,
            text, emb, out0, Wih1f, bih1f, Wih1b, bih1b,
            gxb[ci & 1], gxb[(ci - 1) & 1], Whh1f, bhh1f, Whh1b, bhh1b,
            lens, out0, hcar, hlast, sumb, maxb);
    fused_kernel<2*HH, false><<<NS, 256, 0, stream>>>(0, NC - 1, NS,
        text, emb, out0, Wih1f, bih1f, Wih1b, bih1b,
        gxb[0], gxb[(NC - 1) & 1], Whh1f, bhh1f, Whh1b, bhh1b,
        lens, out0, hcar, hlast, sumb, maxb);

    // ---- head ----
    fc_kernel<<<BB, 128, 0, stream>>>(hlast, sumb, maxb, lens,
        fc1W, fc1b, fc2W, fc2b, out);
}